// Round 9
// baseline (443.567 us; speedup 1.0000x reference)
//
#include <hip/hip_runtime.h>

#define HH 512
#define WW 512
#define NB 8
#define TH 32
#define TW 64
#define ST 80      // LDS row stride in floats (16B-aligned rows)
#define RB 48      // LDS rows per buffer
#define RO 8       // buffer row 8  <-> tile row r0
#define CO 8       // buffer col 8  <-> tile col c0

__device__ __forceinline__ float rcp_f(float x)  { return __builtin_amdgcn_rcpf(x); }
__device__ __forceinline__ float log2_f(float x) { return __builtin_amdgcn_logf(x); }
__device__ __forceinline__ float exp2_f(float x) { return __builtin_amdgcn_exp2f(x); }

#define C1      0.034657359027997264f   /* EPS*ln2       */
#define LOG2_9  3.1699250014423126f
#define NEG_INV -28.853900817779268f    /* -1/(EPS*ln2)  */

__device__ __forceinline__ float4 ld4(const float* p) { return *(const float4*)p; }
__device__ __forceinline__ void   st4(float* p, float4 v) { *(float4*)p = v; }

// One fused step, absolute LDS coords. P holds u_k on entry, u_{k+1} on exit.
// Q is scratch (h-sums, then rcp-h-sums). Halo values at out-of-image
// positions are computed AT the clamped position (edge blocks, scalar path)
// so replicate-pad stays exact recursively.
template<int B_, bool LAST, bool E_IMG, bool WRITEU>
__device__ __forceinline__ void one_step(
    float* __restrict__ P, float* __restrict__ Q,
    int r0, int c0, int tid, bool edge,
    float* __restrict__ uog, const float* __restrict__ imgb,
    float4 (&sk)[2])
{
    constexpr int BC0 = (B_ == 5) ? 0 : 4;            // first col-group
    constexpr int BCL = ((71 + B_) >> 2) << 2;        // last col-group
    constexpr int NG  = (BCL - BC0) / 4 + 1;          // groups per row
    constexpr int RA0 = RO - 1 - B_;                  // phase A rows [RA0,RA1)
    constexpr int NRA = TH + 2 + 2 * B_;
    constexpr int RB0 = RO - B_;                      // phase B rows [RB0,RB1)
    constexpr int NRB = TH + 2 * B_;

    // hoist e = -C1*log2(u_k) before P is overwritten in phase B
    float4 e[2];
    if constexpr (!E_IMG) {
        #pragma unroll
        for (int j = 0; j < 2; ++j) {
            int gi = j * 256 + tid;
            int tr = RO + (gi >> 4), bc = CO + (gi & 15) * 4;
            float4 u = ld4(P + tr * ST + bc);
            e[j].x = -C1 * log2_f(u.x); e[j].y = -C1 * log2_f(u.y);
            e[j].z = -C1 * log2_f(u.z); e[j].w = -C1 * log2_f(u.w);
        }
    }

    // phase A: Q[r][c] = P[r][c-1]+P[r][c]+P[r][c+1]  (centered h-sums)
    for (int gi = tid; gi < NRA * NG; gi += 256) {
        int rr = gi / NG;
        int bc = BC0 + (gi - rr * NG) * 4;
        const float* row = P + (RA0 + rr) * ST;
        float4 q = ld4(row + bc);
        float pm1 = row[bc > 0 ? bc - 1 : 0];
        float p4  = row[bc + 4];
        float4 o;
        o.x = pm1 + q.x + q.y; o.y = q.x + q.y + q.z;
        o.z = q.y + q.z + q.w; o.w = q.z + q.w + p4;
        st4(Q + (RA0 + rr) * ST + bc, o);
    }
    __syncthreads();

    // phase B: P[r][c] = (Q[r-1][c]+Q[r][c]+Q[r+1][c]) / 9   (u_{k+1})
    if (!edge) {
        for (int gi = tid; gi < NRB * NG; gi += 256) {
            int rr = gi / NG;
            int bc = BC0 + (gi - rr * NG) * 4;
            int r = RB0 + rr;
            const float* h = Q + (r - 1) * ST + bc;
            float4 t = ld4(h), m = ld4(h + ST), b = ld4(h + 2 * ST);
            float4 u;
            u.x = (t.x + m.x + b.x) * (1.0f / 9.0f);
            u.y = (t.y + m.y + b.y) * (1.0f / 9.0f);
            u.z = (t.z + m.z + b.z) * (1.0f / 9.0f);
            u.w = (t.w + m.w + b.w) * (1.0f / 9.0f);
            st4(P + r * ST + bc, u);
            if constexpr (LAST && WRITEU) {
                if (r >= RO && r < RO + TH && bc >= CO && bc < CO + TW)
                    *(float4*)(uog + (size_t)(r0 + r - RO) * WW + (c0 + bc - CO)) = u;
            }
        }
    } else {
        constexpr int WID = TW + 2 * B_;
        for (int i = tid; i < NRB * WID; i += 256) {
            int rr = i / WID;
            int c  = (CO - B_) + (i - rr * WID);
            int r  = RB0 + rr;
            int gr = r0 + r - RO, gc = c0 + c - CO;
            int rcl = min(max(gr, 0), HH - 1) - r0 + RO;
            int ccl = min(max(gc, 0), WW - 1) - c0 + CO;
            float u = (Q[(rcl - 1) * ST + ccl] + Q[rcl * ST + ccl] + Q[(rcl + 1) * ST + ccl]) * (1.0f / 9.0f);
            P[r * ST + c] = u;
            if constexpr (LAST && WRITEU) {
                if (r >= RO && r < RO + TH && c >= CO && c < CO + TW)
                    uog[(size_t)gr * WW + gc] = u;
            }
        }
    }
    __syncthreads();

    // phase C: Q[r][c] = rcp(P[r][c-1])+rcp(P[r][c])+rcp(P[r][c+1]),
    //          rows [RO-1, RO+TH+1), cols [CO, CO+TW)
    for (int gi = tid; gi < (TH + 2) * 16; gi += 256) {
        int rr = gi >> 4;
        int bc = CO + (gi & 15) * 4;
        const float* row = P + (RO - 1 + rr) * ST;
        float4 q = ld4(row + bc);
        float pm1 = row[bc - 1], p4 = row[bc + 4];
        float a0 = rcp_f(pm1), a1 = rcp_f(q.x), a2 = rcp_f(q.y),
              a3 = rcp_f(q.z), a4 = rcp_f(q.w), a5 = rcp_f(p4);
        float4 o;
        o.x = a0 + a1 + a2; o.y = a1 + a2 + a3;
        o.z = a2 + a3 + a4; o.w = a3 + a4 + a5;
        st4(Q + (RO - 1 + rr) * ST + bc, o);
    }
    __syncthreads();

    // phase D: dilate v-sum, log, clip, skel accumulate
    #pragma unroll
    for (int j = 0; j < 2; ++j) {
        int gi = j * 256 + tid;
        int tr = RO + (gi >> 4), bc = CO + (gi & 15) * 4;
        const float* h = Q + (tr - 1) * ST + bc;
        float4 t = ld4(h), m = ld4(h + ST), b = ld4(h + 2 * ST);
        float4 d;
        d.x = fminf(fmaxf(C1 * (log2_f(t.x + m.x + b.x) - LOG2_9), 0.0f), 1.0f);
        d.y = fminf(fmaxf(C1 * (log2_f(t.y + m.y + b.y) - LOG2_9), 0.0f), 1.0f);
        d.z = fminf(fmaxf(C1 * (log2_f(t.z + m.z + b.z) - LOG2_9), 0.0f), 1.0f);
        d.w = fminf(fmaxf(C1 * (log2_f(t.w + m.w + b.w) - LOG2_9), 0.0f), 1.0f);
        float4 ee;
        if constexpr (E_IMG)
            ee = *(const float4*)(imgb + (size_t)(r0 + tr - RO) * WW + (c0 + bc - CO));
        else
            ee = e[j];
        sk[j].x += fmaxf(ee.x - d.x, 0.0f);
        sk[j].y += fmaxf(ee.y - d.y, 0.0f);
        sk[j].z += fmaxf(ee.z - d.z, 0.0f);
        sk[j].w += fmaxf(ee.w - d.w, 0.0f);
    }
    __syncthreads();
}

template<int B_, int REMAIN, bool E_IMG, bool WRITEU>
struct Chain {
    static __device__ __forceinline__ void run(
        float* P, float* Q, int r0, int c0, int tid, bool edge,
        float* uog, const float* imgb, float4 (&sk)[2])
    {
        one_step<B_, (REMAIN == 1), E_IMG, WRITEU>(P, Q, r0, c0, tid, edge, uog, imgb, sk);
        if constexpr (REMAIN > 1)
            Chain<B_ - 1, REMAIN - 1, false, WRITEU>::run(P, Q, r0, c0, tid, edge, uog, imgb, sk);
    }
};

template<bool FIRST, int NSTEP, bool WRITEU>
__global__ __launch_bounds__(256)   // NOTE: no min-waves clamp — (256,5) forced
                                    // VGPR<=~102 -> scratch spills (r8: VGPR 48,
                                    // WRITE 86MB/dispatch, VALUBusy 7%)
void sk_fused(const float* __restrict__ u_in, const float* __restrict__ img,
              float* __restrict__ u_out, float* __restrict__ skel)
{
    constexpr int A0 = NSTEP + 1;
    __shared__ __align__(16) float P[RB * ST];   // 15.0 KB
    __shared__ __align__(16) float Q[RB * ST];   // 15.0 KB  (30.0 KB -> 5 blk/CU by LDS)

    const int r0  = blockIdx.y * TH;
    const int c0  = blockIdx.x * TW;
    const int tid = threadIdx.x;
    const bool edge = (blockIdx.x == 0) | (blockIdx.x == gridDim.x - 1) |
                      (blockIdx.y == 0) | (blockIdx.y == gridDim.y - 1);
    const size_t boff = (size_t)blockIdx.z * (HH * WW);
    const float* imgb = img + boff;
    float* uog = u_out + boff;
    float* skb = skel + boff;

    // stage u_k at halo A0, clamped replicate (scalar; once per 5 steps)
    {
        constexpr int SH = TH + 2 * A0, SW = TW + 2 * A0;
        const float* uin = u_in + boff;
        for (int i = tid; i < SH * SW; i += 256) {
            int rr = i / SW, cc = i - rr * SW;
            int gr = min(max(r0 + rr - A0, 0), HH - 1);
            int gc = min(max(c0 + cc - A0, 0), WW - 1);
            float v;
            if constexpr (FIRST) v = exp2_f(imgb[gr * WW + gc] * NEG_INV);
            else                 v = uin[gr * WW + gc];
            P[(RO - A0 + rr) * ST + (CO - A0 + cc)] = v;
        }
    }
    __syncthreads();

    float4 sk[2];
    sk[0] = make_float4(0.f, 0.f, 0.f, 0.f);
    sk[1] = make_float4(0.f, 0.f, 0.f, 0.f);

    Chain<NSTEP, NSTEP, FIRST, WRITEU>::run(P, Q, r0, c0, tid, edge, uog, imgb, sk);

    #pragma unroll
    for (int j = 0; j < 2; ++j) {
        int gi = j * 256 + tid;
        int tr = RO + (gi >> 4), bc = CO + (gi & 15) * 4;
        float* sp = skb + (size_t)(r0 + tr - RO) * WW + (c0 + bc - CO);
        if constexpr (FIRST) {
            *(float4*)sp = sk[j];
        } else {
            float4 old = *(const float4*)sp;
            old.x += sk[j].x; old.y += sk[j].y; old.z += sk[j].z; old.w += sk[j].w;
            *(float4*)sp = old;
        }
    }
}

extern "C" void kernel_launch(void* const* d_in, const int* in_sizes, int n_in,
                              void* d_out, int out_size, void* d_ws, size_t ws_size,
                              hipStream_t stream) {
    const float* img = (const float*)d_in[0];
    float* skel = (float*)d_out;
    const size_t N = (size_t)NB * HH * WW;
    float* ua = (float*)d_ws;
    float* ub = ua + N;                       // 16.8 MB of ws used

    dim3 grid(WW / TW, HH / TH, NB);          // (8,16,8) = 1024 blocks

    // steps 0..4 (e_0 = img exactly), writes u5
    sk_fused<true, 5, true><<<grid, 256, 0, stream>>>(nullptr, img, ua, skel);

    // steps 5..49 in 9 kernels of 5
    float* uin = ua; float* uout = ub;
    for (int t = 0; t < 9; ++t) {
        sk_fused<false, 5, true><<<grid, 256, 0, stream>>>(uin, img, uout, skel);
        float* tmp = uin; uin = uout; uout = tmp;
    }

    // step 50 (no u write needed)
    sk_fused<false, 1, false><<<grid, 256, 0, stream>>>(uin, img, uout, skel);
}